// Round 7
// baseline (101.061 us; speedup 1.0000x reference)
//
#include <hip/hip_runtime.h>
#include <hip/hip_bf16.h>
#include <cstdint>

#define LN2F 0.69314718056f

__device__ __forceinline__ float ssp(float x) {
    return fmaxf(x, 0.0f) + log1pf(expf(-fabsf(x))) - LN2F;
}

__device__ __forceinline__ uint16_t f2bf_rne(float x) {
    uint32_t u = __float_as_uint(x);
    u += 0x7FFF + ((u >> 16) & 1u);
    return (uint16_t)(u >> 16);
}

__device__ __forceinline__ float bf_lo(uint32_t u) { return __uint_as_float(u << 16); }
__device__ __forceinline__ float bf_hi(uint32_t u) { return __uint_as_float(u & 0xffff0000u); }

// ---------------------------------------------------------------------------
// Register-tiled row-linear: thread owns 1 row x 4 cols.
// xrow: LDS pointer to this row's 256 activations (reads are wave-uniform
// broadcasts, 1 ds_read_b128 per 4 k). W streamed as float4/lane (coalesced
// 1 KB/wave/k-row) with 1-group prefetch. rot: per-block k-phase rotation.
// ---------------------------------------------------------------------------
__device__ __forceinline__ void gemm_row4(
    const float* __restrict__ xrow, const float* __restrict__ W,
    int c4, int rot, float acc[4]) {
    float4 w[4], wn[4];
    {
        const int kt0 = rot * 16;
        #pragma unroll
        for (int q = 0; q < 4; ++q) w[q] = *(const float4*)&W[(kt0 + q) * 256 + c4];
    }
    #pragma unroll 4
    for (int g = 0; g < 64; ++g) {
        const int kcur = (((rot + (g >> 2)) & 15) << 4) + ((g & 3) << 2);
        if (g < 63) {
            const int gn = g + 1;
            const int kn = (((rot + (gn >> 2)) & 15) << 4) + ((gn & 3) << 2);
            #pragma unroll
            for (int q = 0; q < 4; ++q) wn[q] = *(const float4*)&W[(kn + q) * 256 + c4];
        }
        const float4 xv = *(const float4*)&xrow[kcur];
        acc[0] = fmaf(xv.x, w[0].x, acc[0]); acc[0] = fmaf(xv.y, w[1].x, acc[0]);
        acc[0] = fmaf(xv.z, w[2].x, acc[0]); acc[0] = fmaf(xv.w, w[3].x, acc[0]);
        acc[1] = fmaf(xv.x, w[0].y, acc[1]); acc[1] = fmaf(xv.y, w[1].y, acc[1]);
        acc[1] = fmaf(xv.z, w[2].y, acc[1]); acc[1] = fmaf(xv.w, w[3].y, acc[1]);
        acc[2] = fmaf(xv.x, w[0].z, acc[2]); acc[2] = fmaf(xv.y, w[1].z, acc[2]);
        acc[2] = fmaf(xv.z, w[2].z, acc[2]); acc[2] = fmaf(xv.w, w[3].z, acc[2]);
        acc[3] = fmaf(xv.x, w[0].w, acc[3]); acc[3] = fmaf(xv.y, w[1].w, acc[3]);
        acc[3] = fmaf(xv.z, w[2].w, acc[3]); acc[3] = fmaf(xv.w, w[3].w, acc[3]);
        #pragma unroll
        for (int q = 0; q < 4; ++q) w[q] = wn[q];
    }
}

// ---------------------------------------------------------------------------
// prep: blocks [0,512):   v1 = (m*(v@W_a1) + b_a1)*m    (4 rows/block)
//       blocks [512,1024): table T[g][d] = F(g*0.0025)[d] bf16 (8 g/block)
// ---------------------------------------------------------------------------
__global__ __launch_bounds__(256) void prep_kernel(
    const float* __restrict__ v, const float* __restrict__ mask,
    const float* __restrict__ W_a1, const float* __restrict__ b_a1,
    const float* __restrict__ W_s1, const float* __restrict__ b_s1,
    const float* __restrict__ W_s2, const float* __restrict__ b_s2,
    float* __restrict__ v1, uint16_t* __restrict__ T) {
    __shared__ float sA[8][304];   // lin: x rows (first 4); table: rbf
    __shared__ float sB[8][64];    // table: hidden layer
    const int t = threadIdx.x;

    if (blockIdx.x < 512) {
        const int r0 = blockIdx.x * 4;
        const int rg = t >> 6;
        const int c4 = (t & 63) << 2;
        const int r = r0 + rg;
        *(float4*)&sA[rg][c4] = *(const float4*)&v[(size_t)r * 256 + c4];
        __syncthreads();
        float acc[4] = {0.f, 0.f, 0.f, 0.f};
        gemm_row4(&sA[rg][0], W_a1, c4, blockIdx.x & 15, acc);
        const float4 bb = *(const float4*)&b_a1[c4];
        const float m = mask[r];
        float4 o;
        o.x = (acc[0] * m + bb.x) * m;
        o.y = (acc[1] * m + bb.y) * m;
        o.z = (acc[2] * m + bb.z) * m;
        o.w = (acc[3] * m + bb.w) * m;
        *(float4*)&v1[(size_t)r * 256 + c4] = o;
    } else {
        const int g0 = (blockIdx.x - 512) * 8;
        #pragma unroll
        for (int gg = 0; gg < 8; ++gg) {
            for (int rr = t; rr < 300; rr += 256) {
                float d = (float)(g0 + gg) * 0.0025f;
                float diff = d - 0.1f * (float)rr;
                sA[gg][rr] = expf(-10.f * diff * diff);
            }
        }
        __syncthreads();
        #pragma unroll
        for (int it = 0; it < 2; ++it) {
            int idx = t + it * 256;
            int gg = idx >> 6, c = idx & 63;
            float acc = b_s1[c];
            for (int rr = 0; rr < 300; ++rr)
                acc = fmaf(sA[gg][rr], W_s1[rr * 64 + c], acc);
            sB[gg][c] = ssp(acc);
        }
        __syncthreads();
        {
            const int col = t;
            float bb = b_s2[col];
            float val[8];
            #pragma unroll
            for (int q = 0; q < 8; ++q) val[q] = bb;
            for (int c = 0; c < 64; ++c) {
                float w = W_s2[c * 256 + col];
                #pragma unroll
                for (int q = 0; q < 8; ++q) val[q] = fmaf(sB[q][c], w, val[q]);
            }
            #pragma unroll
            for (int q = 0; q < 8; ++q)
                T[(size_t)(g0 + q) * 256 + col] = f2bf_rne(ssp(val[q]));
        }
    }
}

// ---------------------------------------------------------------------------
// gather: 1024 blocks x 256 thr. Block (rq, jq): rows rq*8..+7, j-quarter jq.
// Wave w owns 2 rows (2w, 2w+1) -> one v1 float4 load feeds 2 rows (8 FMA).
// part[jq][r][d] = sum_{j in quarter} T[k(r,j)][d] * v1[b,j,d]
// ---------------------------------------------------------------------------
__global__ __launch_bounds__(256) void gather_kernel(
    const float* __restrict__ dist, const float* __restrict__ v1,
    const uint16_t* __restrict__ T, float* __restrict__ part) {
    __shared__ uint32_t sk[8][64];
    const int t = threadIdx.x;
    const int rq = blockIdx.x >> 2;
    const int jq = blockIdx.x & 3;
    const int r0 = rq * 8;
    const int b  = r0 >> 8;
    const int j0 = jq * 64;

    #pragma unroll
    for (int it = 0; it < 2; ++it) {
        int e = t + it * 256;
        int row = e >> 6, j = e & 63;
        float d = dist[(size_t)(r0 + row) * 256 + j0 + j];
        int k = (int)fmaf(d, 400.f, 0.5f);   // nearest grid point, step 0.0025
        k = min(k, 4095);
        sk[row][j] = (uint32_t)(k << 9);     // byte offset (512 B per table row)
    }
    __syncthreads();

    const int w = t >> 6;            // wave id -> rows 2w, 2w+1
    const int l = t & 63;            // lane -> dims 4l..4l+3
    const int rA = 2 * w, rB = rA + 1;
    float a0 = 0.f, a1 = 0.f, a2 = 0.f, a3 = 0.f;   // row A acc
    float e0 = 0.f, e1 = 0.f, e2 = 0.f, e3 = 0.f;   // row B acc
    const char* Tp = (const char*)T + (l << 3);
    const float* vb = v1 + ((size_t)b << 16) + (size_t)j0 * 256 + (l << 2);

    #pragma unroll 2
    for (int jj = 0; jj < 64; jj += 4) {
        const uint4 kA = *(const uint4*)&sk[rA][jj];
        const uint4 kB = *(const uint4*)&sk[rB][jj];
        const uint32_t kAa[4] = {kA.x, kA.y, kA.z, kA.w};
        const uint32_t kBa[4] = {kB.x, kB.y, kB.z, kB.w};
        #pragma unroll
        for (int u = 0; u < 4; ++u) {
            const uint2 uA = *(const uint2*)(Tp + kAa[u]);
            const uint2 uB = *(const uint2*)(Tp + kBa[u]);
            const float4 vv = *(const float4*)(vb + ((jj + u) << 8));
            a0 = fmaf(bf_lo(uA.x), vv.x, a0);
            a1 = fmaf(bf_hi(uA.x), vv.y, a1);
            a2 = fmaf(bf_lo(uA.y), vv.z, a2);
            a3 = fmaf(bf_hi(uA.y), vv.w, a3);
            e0 = fmaf(bf_lo(uB.x), vv.x, e0);
            e1 = fmaf(bf_hi(uB.x), vv.y, e1);
            e2 = fmaf(bf_lo(uB.y), vv.z, e2);
            e3 = fmaf(bf_hi(uB.y), vv.w, e3);
        }
    }
    float* dA = part + ((size_t)(jq * 2048) + r0 + rA) * 256 + (l << 2);
    float* dB = part + ((size_t)(jq * 2048) + r0 + rB) * 256 + (l << 2);
    *(float4*)dA = make_float4(a0, a1, a2, a3);
    *(float4*)dB = make_float4(e0, e1, e2, e3);
}

// ---------------------------------------------------------------------------
// out: 512 blocks x 256 thr, 4 rows/block. Thread = 1 row x 4 cols.
//   xs = (sum_q part[q]) * m ; y = ssp(xs@W_a2+b)*m ; out = (y@W_a3+b)*m
// ---------------------------------------------------------------------------
__global__ __launch_bounds__(256) void out_kernel(
    const float* __restrict__ part, const float* __restrict__ mask,
    const float* __restrict__ W_a2, const float* __restrict__ b_a2,
    const float* __restrict__ W_a3, const float* __restrict__ b_a3,
    float* __restrict__ out) {
    __shared__ float xs[4][256];
    const int t = threadIdx.x;
    const int r0 = blockIdx.x * 4;
    const int rg = t >> 6;
    const int c4 = (t & 63) << 2;
    const int rot = blockIdx.x & 15;
    const int r = r0 + rg;
    const float m = mask[r];

    {
        const float4 s0 = *(const float4*)&part[((size_t)0 * 2048 + r) * 256 + c4];
        const float4 s1 = *(const float4*)&part[((size_t)1 * 2048 + r) * 256 + c4];
        const float4 s2 = *(const float4*)&part[((size_t)2 * 2048 + r) * 256 + c4];
        const float4 s3 = *(const float4*)&part[((size_t)3 * 2048 + r) * 256 + c4];
        float4 o;
        o.x = (s0.x + s1.x + s2.x + s3.x) * m;
        o.y = (s0.y + s1.y + s2.y + s3.y) * m;
        o.z = (s0.z + s1.z + s2.z + s3.z) * m;
        o.w = (s0.w + s1.w + s2.w + s3.w) * m;
        *(float4*)&xs[rg][c4] = o;
    }
    __syncthreads();

    float acc[4] = {0.f, 0.f, 0.f, 0.f};
    gemm_row4(&xs[rg][0], W_a2, c4, rot, acc);
    const float4 b2 = *(const float4*)&b_a2[c4];
    float4 y;
    y.x = ssp(acc[0] + b2.x) * m;
    y.y = ssp(acc[1] + b2.y) * m;
    y.z = ssp(acc[2] + b2.z) * m;
    y.w = ssp(acc[3] + b2.w) * m;
    __syncthreads();
    *(float4*)&xs[rg][c4] = y;
    __syncthreads();

    float acc3[4] = {0.f, 0.f, 0.f, 0.f};
    gemm_row4(&xs[rg][0], W_a3, c4, rot, acc3);
    const float4 b3 = *(const float4*)&b_a3[c4];
    float4 o;
    o.x = (acc3[0] + b3.x) * m;
    o.y = (acc3[1] + b3.y) * m;
    o.z = (acc3[2] + b3.z) * m;
    o.w = (acc3[3] + b3.w) * m;
    *(float4*)&out[(size_t)r * 256 + c4] = o;
}

// ---------------------------------------------------------------------------
extern "C" void kernel_launch(void* const* d_in, const int* in_sizes, int n_in,
                              void* d_out, int out_size, void* d_ws, size_t ws_size,
                              hipStream_t stream) {
    const float* v    = (const float*)d_in[0];
    const float* dist = (const float*)d_in[1];
    const float* mask = (const float*)d_in[2];
    const float* W_s1 = (const float*)d_in[3];
    const float* b_s1 = (const float*)d_in[4];
    const float* W_s2 = (const float*)d_in[5];
    const float* b_s2 = (const float*)d_in[6];
    const float* W_a1 = (const float*)d_in[7];
    const float* b_a1 = (const float*)d_in[8];
    const float* W_a2 = (const float*)d_in[9];
    const float* b_a2 = (const float*)d_in[10];
    const float* W_a3 = (const float*)d_in[11];
    const float* b_a3 = (const float*)d_in[12];
    float* out = (float*)d_out;

    char* ws = (char*)d_ws;
    float*    v1   = (float*)(ws);                   // 2 MB
    uint16_t* T    = (uint16_t*)(ws + (2u << 20));   // 2 MB bf16 [4096][256]
    float*    part = (float*)(ws + (4u << 20));      // 8 MB f32 [4][2048][256]

    prep_kernel<<<1024, 256, 0, stream>>>(v, mask, W_a1, b_a1, W_s1, b_s1, W_s2, b_s2, v1, T);
    gather_kernel<<<1024, 256, 0, stream>>>(dist, v1, T, part);
    out_kernel<<<512, 256, 0, stream>>>(part, mask, W_a2, b_a2, W_a3, b_a3, out);
}

// Round 8
// 96.897 us; speedup vs baseline: 1.0430x; 1.0430x over previous
//
#include <hip/hip_runtime.h>
#include <hip/hip_bf16.h>
#include <cstdint>

#define LN2F 0.69314718056f

__device__ __forceinline__ float ssp(float x) {
    return fmaxf(x, 0.0f) + log1pf(expf(-fabsf(x))) - LN2F;
}

__device__ __forceinline__ uint16_t f2bf_rne(float x) {
    uint32_t u = __float_as_uint(x);
    u += 0x7FFF + ((u >> 16) & 1u);
    return (uint16_t)(u >> 16);
}

__device__ __forceinline__ float bf_lo(uint32_t u) { return __uint_as_float(u << 16); }
__device__ __forceinline__ float bf_hi(uint32_t u) { return __uint_as_float(u & 0xffff0000u); }

// ---------------------------------------------------------------------------
// k-split half-GEMM: thread owns (k-half, col), 4 rows. x broadcast from LDS
// (1 ds_read_b128 per 4 k per row), weights streamed with 16-row chunk
// prefetch and per-block chunk rotation.
// ---------------------------------------------------------------------------
__device__ __forceinline__ void gemm_half(
    const float xs[4][256], const float* __restrict__ W,
    int col, int kbase, int c0, float acc[4]) {
    float wv[16], wn[16];
    {
        const int kt = kbase + c0 * 16;
        #pragma unroll
        for (int q = 0; q < 16; ++q) wv[q] = W[(kt + q) * 256 + col];
    }
    for (int i = 0; i < 8; ++i) {
        const int kt = kbase + ((c0 + i) & 7) * 16;
        if (i < 7) {
            const int ktn = kbase + ((c0 + i + 1) & 7) * 16;
            #pragma unroll
            for (int q = 0; q < 16; ++q) wn[q] = W[(ktn + q) * 256 + col];
        }
        #pragma unroll
        for (int q4 = 0; q4 < 4; ++q4) {
            const int k = kt + (q4 << 2);
            const float w0 = wv[q4 * 4 + 0], w1 = wv[q4 * 4 + 1];
            const float w2 = wv[q4 * 4 + 2], w3 = wv[q4 * 4 + 3];
            #pragma unroll
            for (int rr = 0; rr < 4; ++rr) {
                const float4 xv = *(const float4*)&xs[rr][k];
                float a = acc[rr];
                a = fmaf(xv.x, w0, a);
                a = fmaf(xv.y, w1, a);
                a = fmaf(xv.z, w2, a);
                a = fmaf(xv.w, w3, a);
                acc[rr] = a;
            }
        }
        if (i < 7) {
            #pragma unroll
            for (int q = 0; q < 16; ++q) wv[q] = wn[q];
        }
    }
}

// ---------------------------------------------------------------------------
// prep (R4 version): blocks [0,256): v1 = (m*(v@W_a1) + b_a1) * m (8 rows)
//                    blocks [256,768): table T[g][d] = F(g*0.0025)[d] bf16
// ---------------------------------------------------------------------------
__global__ __launch_bounds__(512) void prep_kernel(
    const float* __restrict__ v, const float* __restrict__ mask,
    const float* __restrict__ W_a1, const float* __restrict__ b_a1,
    const float* __restrict__ W_s1, const float* __restrict__ b_s1,
    const float* __restrict__ W_s2, const float* __restrict__ b_s2,
    float* __restrict__ v1, uint16_t* __restrict__ T) {
    __shared__ float sA[8][304];
    __shared__ float sB[8][64];
    const int t = threadIdx.x;

    if (blockIdx.x < 256) {
        const int r0 = blockIdx.x * 8;
        for (int e = t; e < 2048; e += 512) {
            int row = e >> 8, c = e & 255;
            sA[row][c] = v[(r0 + row) * 256 + c];
        }
        __syncthreads();
        const int col = t & 255;
        const int g = t >> 8;
        const int c0 = blockIdx.x & 15;
        float acc[4] = {0.f, 0.f, 0.f, 0.f};
        float w[16], wn[16];
        {
            const int kt = c0 * 16;
            #pragma unroll
            for (int q = 0; q < 16; ++q) w[q] = W_a1[(kt + q) * 256 + col];
        }
        for (int i = 0; i < 16; ++i) {
            const int kt = ((c0 + i) & 15) * 16;
            if (i < 15) {
                const int ktn = ((c0 + i + 1) & 15) * 16;
                #pragma unroll
                for (int q = 0; q < 16; ++q) wn[q] = W_a1[(ktn + q) * 256 + col];
            }
            #pragma unroll
            for (int q4 = 0; q4 < 4; ++q4) {
                const int k = kt + q4 * 4;
                const float w0 = w[q4 * 4 + 0], w1 = w[q4 * 4 + 1];
                const float w2 = w[q4 * 4 + 2], w3 = w[q4 * 4 + 3];
                #pragma unroll
                for (int rr = 0; rr < 4; ++rr) {
                    const float4 xv = *(const float4*)&sA[g * 4 + rr][k];
                    float a = acc[rr];
                    a = fmaf(xv.x, w0, a);
                    a = fmaf(xv.y, w1, a);
                    a = fmaf(xv.z, w2, a);
                    a = fmaf(xv.w, w3, a);
                    acc[rr] = a;
                }
            }
            if (i < 15) {
                #pragma unroll
                for (int q = 0; q < 16; ++q) w[q] = wn[q];
            }
        }
        const float b = b_a1[col];
        #pragma unroll
        for (int rr = 0; rr < 4; ++rr) {
            const int r = r0 + g * 4 + rr;
            const float m = mask[r];
            v1[r * 256 + col] = (acc[rr] * m + b) * m;
        }
    } else {
        const int g0 = (blockIdx.x - 256) * 8;
        #pragma unroll
        for (int gg = 0; gg < 8; ++gg) {
            if (t < 300) {
                float d = (float)(g0 + gg) * 0.0025f;
                float diff = d - 0.1f * (float)t;
                sA[gg][t] = expf(-10.f * diff * diff);
            }
        }
        __syncthreads();
        {
            int gg = t >> 6, c = t & 63;
            float acc = b_s1[c];
            for (int r = 0; r < 300; ++r)
                acc = fmaf(sA[gg][r], W_s1[r * 64 + c], acc);
            sB[gg][c] = ssp(acc);
        }
        __syncthreads();
        {
            int col = t & 255, glo = t >> 8;
            float bb = b_s2[col];
            float val[4];
            #pragma unroll
            for (int q = 0; q < 4; ++q) val[q] = bb;
            for (int c = 0; c < 64; ++c) {
                float w = W_s2[c * 256 + col];
                #pragma unroll
                for (int q = 0; q < 4; ++q)
                    val[q] = fmaf(sB[glo + 2 * q][c], w, val[q]);
            }
            #pragma unroll
            for (int q = 0; q < 4; ++q) {
                int g = g0 + glo + 2 * q;
                T[g * 256 + col] = f2bf_rne(ssp(val[q]));
            }
        }
    }
}

// ---------------------------------------------------------------------------
// main: 512 blocks x 512 thr (2 blocks/CU, 16 waves/CU), 4 rows/block.
//  gather: wave pair per row, j-parity split over 32-j LDS tiles of v1;
//          table rows read coalesced (j wave-uniform). LDS reduce.
//  a2, a3: k-split halves, LDS-resident activations.
// ---------------------------------------------------------------------------
__global__ __launch_bounds__(512, 2) void main_kernel(
    const float* __restrict__ dist, const float* __restrict__ v1,
    const uint16_t* __restrict__ T, const float* __restrict__ mask,
    const float* __restrict__ W_a2, const float* __restrict__ b_a2,
    const float* __restrict__ W_a3, const float* __restrict__ b_a3,
    float* __restrict__ out) {
    __shared__ float v1s[32][256];    // 32 KB j-tile
    __shared__ uint32_t sk[4][256];   // 4 KB table byte offsets
    __shared__ float xs[4][256];      // 4 KB activations
    __shared__ float4 red[8][64];     // 8 KB reduce buffer
    const int t = threadIdx.x;
    const int r0 = blockIdx.x * 4;
    const int b = r0 >> 8;
    const int w = t >> 6;             // wave 0..7
    const int l = t & 63;             // lane: dims 4l..4l+3
    const int row = w >> 1;           // 0..3
    const int par = w & 1;            // j-tile parity

    #pragma unroll
    for (int it = 0; it < 2; ++it) {
        int e = t + it * 512;
        int rr = e >> 8, j = e & 255;
        float d = dist[(size_t)(r0 + rr) * 256 + j];
        int k = (int)fmaf(d, 400.f, 0.5f);   // nearest grid point, step 0.0025
        sk[rr][j] = (uint32_t)(min(k, 4095) << 9);
    }

    float4 acc = make_float4(0.f, 0.f, 0.f, 0.f);
    const char* Tp = (const char*)T + (l << 3);
    const float4* srcbase = (const float4*)(v1 + ((size_t)b << 16));

    for (int jt = 0; jt < 256; jt += 32) {
        __syncthreads();                      // prev compute done (also sk, 1st iter)
        const float4* src = srcbase + jt * 64;
        float4* dst = (float4*)v1s;
        #pragma unroll
        for (int u = 0; u < 4; ++u)
            dst[u * 512 + t] = src[u * 512 + t];
        __syncthreads();
        if (((jt >> 5) & 1) == par) {
            #pragma unroll 4
            for (int jj = 0; jj < 32; ++jj) {
                const uint32_t off = sk[row][jt + jj];
                const uint2 u = *(const uint2*)(Tp + off);
                const float4 vv = *(const float4*)&v1s[jj][l << 2];
                acc.x = fmaf(bf_lo(u.x), vv.x, acc.x);
                acc.y = fmaf(bf_hi(u.x), vv.y, acc.y);
                acc.z = fmaf(bf_lo(u.y), vv.z, acc.z);
                acc.w = fmaf(bf_hi(u.y), vv.w, acc.w);
            }
        }
    }
    red[w][l] = acc;
    __syncthreads();
    if (w < 4) {   // reduce wave pair, apply mask
        const float4 s0 = red[2 * w][l];
        const float4 s1 = red[2 * w + 1][l];
        const float m = mask[r0 + w];
        *(float4*)&xs[w][l << 2] = make_float4(
            (s0.x + s1.x) * m, (s0.y + s1.y) * m,
            (s0.z + s1.z) * m, (s0.w + s1.w) * m);
    }
    __syncthreads();

    // ---------------- a2, a3 (k-split halves) ----------------
    const int col = t & 255;
    const int g = t >> 8;
    const int kbase = g << 7;
    const int c0 = blockIdx.x & 7;
    float* redf = (float*)red;

    float acc2[4] = {0.f, 0.f, 0.f, 0.f};
    gemm_half(xs, W_a2, col, kbase, c0, acc2);
    if (g == 1) {
        #pragma unroll
        for (int rr = 0; rr < 4; ++rr) redf[rr * 256 + col] = acc2[rr];
    }
    __syncthreads();
    if (g == 0) {
        const float b2 = b_a2[col];
        #pragma unroll
        for (int rr = 0; rr < 4; ++rr) {
            float a = acc2[rr] + redf[rr * 256 + col] + b2;
            xs[rr][col] = ssp(a) * mask[r0 + rr];
        }
    }
    __syncthreads();

    float acc3[4] = {0.f, 0.f, 0.f, 0.f};
    gemm_half(xs, W_a3, col, kbase, c0, acc3);
    if (g == 1) {
        #pragma unroll
        for (int rr = 0; rr < 4; ++rr) redf[rr * 256 + col] = acc3[rr];
    }
    __syncthreads();
    if (g == 0) {
        const float b3 = b_a3[col];
        #pragma unroll
        for (int rr = 0; rr < 4; ++rr) {
            const int r = r0 + rr;
            out[r * 256 + col] = (acc3[rr] + redf[rr * 256 + col] + b3) * mask[r];
        }
    }
}

// ---------------------------------------------------------------------------
extern "C" void kernel_launch(void* const* d_in, const int* in_sizes, int n_in,
                              void* d_out, int out_size, void* d_ws, size_t ws_size,
                              hipStream_t stream) {
    const float* v    = (const float*)d_in[0];
    const float* dist = (const float*)d_in[1];
    const float* mask = (const float*)d_in[2];
    const float* W_s1 = (const float*)d_in[3];
    const float* b_s1 = (const float*)d_in[4];
    const float* W_s2 = (const float*)d_in[5];
    const float* b_s2 = (const float*)d_in[6];
    const float* W_a1 = (const float*)d_in[7];
    const float* b_a1 = (const float*)d_in[8];
    const float* W_a2 = (const float*)d_in[9];
    const float* b_a2 = (const float*)d_in[10];
    const float* W_a3 = (const float*)d_in[11];
    const float* b_a3 = (const float*)d_in[12];
    float* out = (float*)d_out;

    char* ws = (char*)d_ws;
    float*    v1 = (float*)(ws);                   // 2 MB
    uint16_t* T  = (uint16_t*)(ws + (2u << 20));   // 2 MB bf16 [4096][256]

    prep_kernel<<<768, 512, 0, stream>>>(v, mask, W_a1, b_a1, W_s1, b_s1, W_s2, b_s2, v1, T);
    main_kernel<<<512, 512, 0, stream>>>(dist, v1, T, mask, W_a2, b_a2, W_a3, b_a3, out);
}

// Round 9
// 87.044 us; speedup vs baseline: 1.1610x; 1.1132x over previous
//
#include <hip/hip_runtime.h>
#include <hip/hip_bf16.h>
#include <cstdint>

#define LN2F 0.69314718056f

__device__ __forceinline__ float ssp(float x) {
    return fmaxf(x, 0.0f) + log1pf(expf(-fabsf(x))) - LN2F;
}

__device__ __forceinline__ uint16_t f2bf_rne(float x) {
    uint32_t u = __float_as_uint(x);
    u += 0x7FFF + ((u >> 16) & 1u);
    return (uint16_t)(u >> 16);
}

__device__ __forceinline__ float bf_lo(uint32_t u) { return __uint_as_float(u << 16); }
__device__ __forceinline__ float bf_hi(uint32_t u) { return __uint_as_float(u & 0xffff0000u); }

// ---------------------------------------------------------------------------
// prep: blocks [0,512):   v1 = (m*(v@W_a1)+b_a1)*m ; 4 rows/block, thread=col.
//                         No LDS, no barriers: x via uniform scalar loads.
//       blocks [512,1024): table T[g][d] = F(g*0.0025)[d] bf16, 8 g/block.
// ---------------------------------------------------------------------------
__global__ __launch_bounds__(256) void prep_kernel(
    const float* __restrict__ v, const float* __restrict__ mask,
    const float* __restrict__ W_a1, const float* __restrict__ b_a1,
    const float* __restrict__ W_s1, const float* __restrict__ b_s1,
    const float* __restrict__ W_s2, const float* __restrict__ b_s2,
    float* __restrict__ v1, uint16_t* __restrict__ T) {
    __shared__ float sA[8][304];
    __shared__ float sB[8][64];
    const int t = threadIdx.x;

    if (blockIdx.x < 512) {
        const int r0 = blockIdx.x * 4;
        const int col = t;
        const int kofs = (blockIdx.x & 15) << 4;   // de-hotspot L2
        float acc[4] = {0.f, 0.f, 0.f, 0.f};
        #pragma unroll 8
        for (int i = 0; i < 256; ++i) {
            const int k = (i + kofs) & 255;
            const float wv = W_a1[k * 256 + col];
            acc[0] = fmaf(v[(r0 + 0) * 256 + k], wv, acc[0]);
            acc[1] = fmaf(v[(r0 + 1) * 256 + k], wv, acc[1]);
            acc[2] = fmaf(v[(r0 + 2) * 256 + k], wv, acc[2]);
            acc[3] = fmaf(v[(r0 + 3) * 256 + k], wv, acc[3]);
        }
        const float b = b_a1[col];
        #pragma unroll
        for (int rr = 0; rr < 4; ++rr) {
            const int r = r0 + rr;
            const float m = mask[r];
            v1[(size_t)r * 256 + col] = (acc[rr] * m + b) * m;
        }
    } else {
        const int g0 = (blockIdx.x - 512) * 8;
        #pragma unroll
        for (int gg = 0; gg < 8; ++gg) {
            for (int rr = t; rr < 300; rr += 256) {
                float d = (float)(g0 + gg) * 0.0025f;
                float diff = d - 0.1f * (float)rr;
                sA[gg][rr] = expf(-10.f * diff * diff);
            }
        }
        __syncthreads();
        #pragma unroll
        for (int it = 0; it < 2; ++it) {
            int idx = t + it * 256;
            int gg = idx >> 6, c = idx & 63;
            float acc = b_s1[c];
            for (int rr = 0; rr < 300; ++rr)
                acc = fmaf(sA[gg][rr], W_s1[rr * 64 + c], acc);
            sB[gg][c] = ssp(acc);
        }
        __syncthreads();
        {
            const int col = t;
            float bb = b_s2[col];
            float val[8];
            #pragma unroll
            for (int q = 0; q < 8; ++q) val[q] = bb;
            for (int c = 0; c < 64; ++c) {
                float w = W_s2[c * 256 + col];
                #pragma unroll
                for (int q = 0; q < 8; ++q) val[q] = fmaf(sB[q][c], w, val[q]);
            }
            #pragma unroll
            for (int q = 0; q < 8; ++q)
                T[(size_t)(g0 + q) * 256 + col] = f2bf_rne(ssp(val[q]));
        }
    }
}

// ---------------------------------------------------------------------------
// gather: 2048 blocks x 256 thr = 32 waves/CU (100% occupancy cap).
// Block (rq, jq): rows rq*4..+3, j in [jq*64, jq*64+64). Wave = one row.
// One barrier total; inner loop barrier-free, ~8 loads in flight.
//   part[jq][r][d] = sum_{j in quarter} T[k(r,j)][d] * v1[b,j,d]
// ---------------------------------------------------------------------------
__global__ __launch_bounds__(256, 8) void gather_kernel(
    const float* __restrict__ dist, const float* __restrict__ v1,
    const uint16_t* __restrict__ T, float* __restrict__ part) {
    __shared__ uint32_t sk[4][64];
    const int t = threadIdx.x;
    const int rq = blockIdx.x >> 2;
    const int jq = blockIdx.x & 3;
    const int r0 = rq * 4;
    const int b  = r0 >> 8;
    const int j0 = jq * 64;

    {
        int row = t >> 6, j = t & 63;
        float d = dist[(size_t)(r0 + row) * 256 + j0 + j];
        int k = (int)fmaf(d, 400.f, 0.5f);   // nearest grid point, step 0.0025
        sk[row][j] = (uint32_t)(min(k, 4095) << 9);   // byte offset, 512 B/row
    }
    __syncthreads();

    const int w = t >> 6;   // wave -> row
    const int l = t & 63;   // lane -> dims 4l..4l+3
    float4 acc = make_float4(0.f, 0.f, 0.f, 0.f);
    const char* Tp = (const char*)T + (l << 3);
    const float* vb = v1 + ((size_t)b << 16) + (size_t)j0 * 256 + (l << 2);

    #pragma unroll 4
    for (int jj = 0; jj < 64; ++jj) {
        const uint32_t off = sk[w][jj];
        const uint2 u = *(const uint2*)(Tp + off);
        const float4 vv = *(const float4*)(vb + (jj << 8));
        acc.x = fmaf(bf_lo(u.x), vv.x, acc.x);
        acc.y = fmaf(bf_hi(u.x), vv.y, acc.y);
        acc.z = fmaf(bf_lo(u.y), vv.z, acc.z);
        acc.w = fmaf(bf_hi(u.y), vv.w, acc.w);
    }
    float* dst = part + ((size_t)jq * 2048 + r0 + w) * 256 + (l << 2);
    *(float4*)dst = acc;
}

// ---------------------------------------------------------------------------
// out: 512 blocks x 512 thr (16 waves/CU), 4 rows/block, col-split:
// thread = (g = t>>8 -> rows 2g,2g+1) x (col = t&255), full k, no k-reduce.
//   xs = (sum_q part[q]) * m ; y = ssp(xs@W_a2+b)*m ; out = (y@W_a3+b)*m
// ---------------------------------------------------------------------------
__global__ __launch_bounds__(512) void out_kernel(
    const float* __restrict__ part, const float* __restrict__ mask,
    const float* __restrict__ W_a2, const float* __restrict__ b_a2,
    const float* __restrict__ W_a3, const float* __restrict__ b_a3,
    float* __restrict__ out) {
    __shared__ float xs[4][256];
    const int t = threadIdx.x;
    const int r0 = blockIdx.x * 4;
    const int col = t & 255;
    const int g = t >> 8;                     // rows 2g, 2g+1
    const int rA = r0 + 2 * g, rB = rA + 1;
    const int c4ofs = (blockIdx.x & 15) << 2; // rotation in float4 groups

    #pragma unroll
    for (int it = 0; it < 2; ++it) {          // reduce partials -> xs
        int e = t + it * 512;
        int row = e >> 8, c = e & 255;
        int r = r0 + row;
        float s = part[((size_t)0 * 2048 + r) * 256 + c]
                + part[((size_t)1 * 2048 + r) * 256 + c]
                + part[((size_t)2 * 2048 + r) * 256 + c]
                + part[((size_t)3 * 2048 + r) * 256 + c];
        xs[row][c] = s * mask[r];
    }
    __syncthreads();

    // ---------------- a2 ----------------
    float a0 = 0.f, a1 = 0.f;
    #pragma unroll 4
    for (int i4 = 0; i4 < 64; ++i4) {
        const int k = (((i4 + c4ofs) & 63) << 2);
        const float4 xA = *(const float4*)&xs[2 * g][k];
        const float4 xB = *(const float4*)&xs[2 * g + 1][k];
        const float w0 = W_a2[(k + 0) * 256 + col];
        const float w1 = W_a2[(k + 1) * 256 + col];
        const float w2 = W_a2[(k + 2) * 256 + col];
        const float w3 = W_a2[(k + 3) * 256 + col];
        a0 = fmaf(xA.x, w0, a0); a0 = fmaf(xA.y, w1, a0);
        a0 = fmaf(xA.z, w2, a0); a0 = fmaf(xA.w, w3, a0);
        a1 = fmaf(xB.x, w0, a1); a1 = fmaf(xB.y, w1, a1);
        a1 = fmaf(xB.z, w2, a1); a1 = fmaf(xB.w, w3, a1);
    }
    const float b2 = b_a2[col];
    const float y0 = ssp(a0 + b2) * mask[rA];
    const float y1 = ssp(a1 + b2) * mask[rB];
    __syncthreads();
    xs[2 * g][col] = y0;
    xs[2 * g + 1][col] = y1;
    __syncthreads();

    // ---------------- a3 ----------------
    float c0 = 0.f, c1 = 0.f;
    #pragma unroll 4
    for (int i4 = 0; i4 < 64; ++i4) {
        const int k = (((i4 + c4ofs) & 63) << 2);
        const float4 xA = *(const float4*)&xs[2 * g][k];
        const float4 xB = *(const float4*)&xs[2 * g + 1][k];
        const float w0 = W_a3[(k + 0) * 256 + col];
        const float w1 = W_a3[(k + 1) * 256 + col];
        const float w2 = W_a3[(k + 2) * 256 + col];
        const float w3 = W_a3[(k + 3) * 256 + col];
        c0 = fmaf(xA.x, w0, c0); c0 = fmaf(xA.y, w1, c0);
        c0 = fmaf(xA.z, w2, c0); c0 = fmaf(xA.w, w3, c0);
        c1 = fmaf(xB.x, w0, c1); c1 = fmaf(xB.y, w1, c1);
        c1 = fmaf(xB.z, w2, c1); c1 = fmaf(xB.w, w3, c1);
    }
    const float b3 = b_a3[col];
    out[(size_t)rA * 256 + col] = (c0 + b3) * mask[rA];
    out[(size_t)rB * 256 + col] = (c1 + b3) * mask[rB];
}

// ---------------------------------------------------------------------------
extern "C" void kernel_launch(void* const* d_in, const int* in_sizes, int n_in,
                              void* d_out, int out_size, void* d_ws, size_t ws_size,
                              hipStream_t stream) {
    const float* v    = (const float*)d_in[0];
    const float* dist = (const float*)d_in[1];
    const float* mask = (const float*)d_in[2];
    const float* W_s1 = (const float*)d_in[3];
    const float* b_s1 = (const float*)d_in[4];
    const float* W_s2 = (const float*)d_in[5];
    const float* b_s2 = (const float*)d_in[6];
    const float* W_a1 = (const float*)d_in[7];
    const float* b_a1 = (const float*)d_in[8];
    const float* W_a2 = (const float*)d_in[9];
    const float* b_a2 = (const float*)d_in[10];
    const float* W_a3 = (const float*)d_in[11];
    const float* b_a3 = (const float*)d_in[12];
    float* out = (float*)d_out;

    char* ws = (char*)d_ws;
    float*    v1   = (float*)(ws);                   // 2 MB
    uint16_t* T    = (uint16_t*)(ws + (2u << 20));   // 2 MB bf16 [4096][256]
    float*    part = (float*)(ws + (4u << 20));      // 8 MB f32 [4][2048][256]

    prep_kernel<<<1024, 256, 0, stream>>>(v, mask, W_a1, b_a1, W_s1, b_s1, W_s2, b_s2, v1, T);
    gather_kernel<<<2048, 256, 0, stream>>>(dist, v1, T, part);
    out_kernel<<<512, 512, 0, stream>>>(part, mask, W_a2, b_a2, W_a3, b_a3, out);
}

// Round 11
// 73.309 us; speedup vs baseline: 1.3786x; 1.1874x over previous
//
#include <hip/hip_runtime.h>
#include <hip/hip_bf16.h>
#include <cstdint>

#define LN2F 0.69314718056f

__device__ __forceinline__ float ssp(float x) {
    return fmaxf(x, 0.0f) + log1pf(expf(-fabsf(x))) - LN2F;
}

__device__ __forceinline__ uint16_t f2bf_rne(float x) {
    uint32_t u = __float_as_uint(x);
    u += 0x7FFF + ((u >> 16) & 1u);
    return (uint16_t)(u >> 16);
}

__device__ __forceinline__ float bf_lo(uint32_t u) { return __uint_as_float(u << 16); }
__device__ __forceinline__ float bf_hi(uint32_t u) { return __uint_as_float(u & 0xffff0000u); }

// ---------------------------------------------------------------------------
// prep (R4 version, unchanged): blocks [0,256): v1 = (m*(v@W_a1)+b_a1)*m
//                               blocks [256,768): table T[g][d], bf16 NN grid
// ---------------------------------------------------------------------------
__global__ __launch_bounds__(512) void prep_kernel(
    const float* __restrict__ v, const float* __restrict__ mask,
    const float* __restrict__ W_a1, const float* __restrict__ b_a1,
    const float* __restrict__ W_s1, const float* __restrict__ b_s1,
    const float* __restrict__ W_s2, const float* __restrict__ b_s2,
    float* __restrict__ v1, uint16_t* __restrict__ T) {
    __shared__ float sA[8][304];
    __shared__ float sB[8][64];
    const int t = threadIdx.x;

    if (blockIdx.x < 256) {
        const int r0 = blockIdx.x * 8;
        for (int e = t; e < 2048; e += 512) {
            int row = e >> 8, c = e & 255;
            sA[row][c] = v[(r0 + row) * 256 + c];
        }
        __syncthreads();
        const int col = t & 255;
        const int g = t >> 8;
        const int c0 = blockIdx.x & 15;
        float acc[4] = {0.f, 0.f, 0.f, 0.f};
        float w[16], wn[16];
        {
            const int kt = c0 * 16;
            #pragma unroll
            for (int q = 0; q < 16; ++q) w[q] = W_a1[(kt + q) * 256 + col];
        }
        for (int i = 0; i < 16; ++i) {
            const int kt = ((c0 + i) & 15) * 16;
            if (i < 15) {
                const int ktn = ((c0 + i + 1) & 15) * 16;
                #pragma unroll
                for (int q = 0; q < 16; ++q) wn[q] = W_a1[(ktn + q) * 256 + col];
            }
            #pragma unroll
            for (int q4 = 0; q4 < 4; ++q4) {
                const int k = kt + q4 * 4;
                const float w0 = w[q4 * 4 + 0], w1 = w[q4 * 4 + 1];
                const float w2 = w[q4 * 4 + 2], w3 = w[q4 * 4 + 3];
                #pragma unroll
                for (int rr = 0; rr < 4; ++rr) {
                    const float4 xv = *(const float4*)&sA[g * 4 + rr][k];
                    float a = acc[rr];
                    a = fmaf(xv.x, w0, a);
                    a = fmaf(xv.y, w1, a);
                    a = fmaf(xv.z, w2, a);
                    a = fmaf(xv.w, w3, a);
                    acc[rr] = a;
                }
            }
            if (i < 15) {
                #pragma unroll
                for (int q = 0; q < 16; ++q) w[q] = wn[q];
            }
        }
        const float b = b_a1[col];
        #pragma unroll
        for (int rr = 0; rr < 4; ++rr) {
            const int r = r0 + g * 4 + rr;
            const float m = mask[r];
            v1[r * 256 + col] = (acc[rr] * m + b) * m;
        }
    } else {
        const int g0 = (blockIdx.x - 256) * 8;
        #pragma unroll
        for (int gg = 0; gg < 8; ++gg) {
            if (t < 300) {
                float d = (float)(g0 + gg) * 0.0025f;
                float diff = d - 0.1f * (float)t;
                sA[gg][t] = expf(-10.f * diff * diff);
            }
        }
        __syncthreads();
        {
            int gg = t >> 6, c = t & 63;
            float acc = b_s1[c];
            for (int r = 0; r < 300; ++r)
                acc = fmaf(sA[gg][r], W_s1[r * 64 + c], acc);
            sB[gg][c] = ssp(acc);
        }
        __syncthreads();
        {
            int col = t & 255, glo = t >> 8;
            float bb = b_s2[col];
            float val[4];
            #pragma unroll
            for (int q = 0; q < 4; ++q) val[q] = bb;
            for (int c = 0; c < 64; ++c) {
                float w = W_s2[c * 256 + col];
                #pragma unroll
                for (int q = 0; q < 4; ++q)
                    val[q] = fmaf(sB[glo + 2 * q][c], w, val[q]);
            }
            #pragma unroll
            for (int q = 0; q < 4; ++q) {
                int g = g0 + glo + 2 * q;
                T[g * 256 + col] = f2bf_rne(ssp(val[q]));
            }
        }
    }
}

// ---------------------------------------------------------------------------
// main: 512 blocks x 512 thr, 4 rows/block.
// Gather: wave w = (row = w>>1, half = w&1); lane l owns dims
//   d0 = (half<<7) + 2l  (TWO dims per lane -> 64 lanes x 2 = 128 dims/wave).
// Every wave active every tile; disjoint dims -> no cross-wave reduce.
// Per j: 4B table load (2 bf16) + float2 LDS read + 2 FMA.
// Then a2/a3 col-split (2 rows/thread, full k, 16-deep weight prefetch).
// ---------------------------------------------------------------------------
__global__ __launch_bounds__(512) void main_kernel(
    const float* __restrict__ dist, const float* __restrict__ v1,
    const uint16_t* __restrict__ T, const float* __restrict__ mask,
    const float* __restrict__ W_a2, const float* __restrict__ b_a2,
    const float* __restrict__ W_a3, const float* __restrict__ b_a3,
    float* __restrict__ out) {
    __shared__ float v1s[32][256];    // 32 KB j-tile
    __shared__ uint32_t sk[4][256];   // 4 KB table byte offsets
    __shared__ float xs[4][256];      // 4 KB activations
    const int t = threadIdx.x;
    const int r0 = blockIdx.x * 4;
    const int b = r0 >> 8;
    const int w = t >> 6;             // wave 0..7
    const int l = t & 63;
    const int row = w >> 1;           // 0..3
    const int d0 = ((w & 1) << 7) + (l << 1);   // dims d0, d0+1 (max 254)

    #pragma unroll
    for (int it = 0; it < 2; ++it) {
        int e = t + it * 512;
        int rr = e >> 8, j = e & 255;
        float d = dist[(size_t)(r0 + rr) * 256 + j];
        int k = (int)fmaf(d, 400.f, 0.5f);   // nearest grid point, step 0.0025
        sk[rr][j] = (uint32_t)(min(k, 4095) << 9);
    }

    float2 acc = make_float2(0.f, 0.f);
    const char* Tp = (const char*)T + (d0 << 1);   // byte offset d0*2
    const float4* srcbase = (const float4*)(v1 + ((size_t)b << 16));

    for (int jt = 0; jt < 256; jt += 32) {
        __syncthreads();                      // prev compute done (also sk, 1st iter)
        const float4* src = srcbase + jt * 64;
        float4* dst = (float4*)v1s;
        #pragma unroll
        for (int u = 0; u < 4; ++u)
            dst[u * 512 + t] = src[u * 512 + t];
        __syncthreads();
        #pragma unroll 2
        for (int jj = 0; jj < 32; jj += 4) {
            const uint4 kk = *(const uint4*)&sk[row][jt + jj];
            const uint32_t u0 = *(const uint32_t*)(Tp + kk.x);
            const uint32_t u1 = *(const uint32_t*)(Tp + kk.y);
            const uint32_t u2 = *(const uint32_t*)(Tp + kk.z);
            const uint32_t u3 = *(const uint32_t*)(Tp + kk.w);
            const float2 w0 = *(const float2*)&v1s[jj + 0][d0];
            const float2 w1 = *(const float2*)&v1s[jj + 1][d0];
            const float2 w2 = *(const float2*)&v1s[jj + 2][d0];
            const float2 w3 = *(const float2*)&v1s[jj + 3][d0];
            acc.x = fmaf(bf_lo(u0), w0.x, acc.x);
            acc.y = fmaf(bf_hi(u0), w0.y, acc.y);
            acc.x = fmaf(bf_lo(u1), w1.x, acc.x);
            acc.y = fmaf(bf_hi(u1), w1.y, acc.y);
            acc.x = fmaf(bf_lo(u2), w2.x, acc.x);
            acc.y = fmaf(bf_hi(u2), w2.y, acc.y);
            acc.x = fmaf(bf_lo(u3), w3.x, acc.x);
            acc.y = fmaf(bf_hi(u3), w3.y, acc.y);
        }
    }
    __syncthreads();
    {   // disjoint dims per wave -> direct write, no reduce
        const float m = mask[r0 + row];
        *(float2*)&xs[row][d0] = make_float2(acc.x * m, acc.y * m);
    }
    __syncthreads();

    // ---------------- a2 then a3 (col-split, 2 rows/thread) ----------------
    const int col = t & 255;
    const int gg = t >> 8;               // rows 2gg, 2gg+1
    const int rA = r0 + 2 * gg, rB = rA + 1;
    const int c0 = blockIdx.x & 15;

    float a0 = 0.f, a1 = 0.f;
    {
        float wv[16], wn[16];
        {
            const int kt = c0 * 16;
            #pragma unroll
            for (int q = 0; q < 16; ++q) wv[q] = W_a2[(kt + q) * 256 + col];
        }
        for (int i = 0; i < 16; ++i) {
            const int kt = ((c0 + i) & 15) * 16;
            if (i < 15) {
                const int ktn = ((c0 + i + 1) & 15) * 16;
                #pragma unroll
                for (int q = 0; q < 16; ++q) wn[q] = W_a2[(ktn + q) * 256 + col];
            }
            #pragma unroll
            for (int q4 = 0; q4 < 4; ++q4) {
                const int k = kt + (q4 << 2);
                const float4 xA = *(const float4*)&xs[2 * gg][k];
                const float4 xB = *(const float4*)&xs[2 * gg + 1][k];
                const float w0 = wv[q4 * 4 + 0], w1 = wv[q4 * 4 + 1];
                const float w2 = wv[q4 * 4 + 2], w3 = wv[q4 * 4 + 3];
                a0 = fmaf(xA.x, w0, a0); a0 = fmaf(xA.y, w1, a0);
                a0 = fmaf(xA.z, w2, a0); a0 = fmaf(xA.w, w3, a0);
                a1 = fmaf(xB.x, w0, a1); a1 = fmaf(xB.y, w1, a1);
                a1 = fmaf(xB.z, w2, a1); a1 = fmaf(xB.w, w3, a1);
            }
            if (i < 15) {
                #pragma unroll
                for (int q = 0; q < 16; ++q) wv[q] = wn[q];
            }
        }
    }
    const float b2 = b_a2[col];
    const float y0 = ssp(a0 + b2) * mask[rA];
    const float y1 = ssp(a1 + b2) * mask[rB];
    __syncthreads();
    xs[2 * gg][col] = y0;
    xs[2 * gg + 1][col] = y1;
    __syncthreads();

    float c0a = 0.f, c1a = 0.f;
    {
        float wv[16], wn[16];
        {
            const int kt = c0 * 16;
            #pragma unroll
            for (int q = 0; q < 16; ++q) wv[q] = W_a3[(kt + q) * 256 + col];
        }
        for (int i = 0; i < 16; ++i) {
            const int kt = ((c0 + i) & 15) * 16;
            if (i < 15) {
                const int ktn = ((c0 + i + 1) & 15) * 16;
                #pragma unroll
                for (int q = 0; q < 16; ++q) wn[q] = W_a3[(ktn + q) * 256 + col];
            }
            #pragma unroll
            for (int q4 = 0; q4 < 4; ++q4) {
                const int k = kt + (q4 << 2);
                const float4 xA = *(const float4*)&xs[2 * gg][k];
                const float4 xB = *(const float4*)&xs[2 * gg + 1][k];
                const float w0 = wv[q4 * 4 + 0], w1 = wv[q4 * 4 + 1];
                const float w2 = wv[q4 * 4 + 2], w3 = wv[q4 * 4 + 3];
                c0a = fmaf(xA.x, w0, c0a); c0a = fmaf(xA.y, w1, c0a);
                c0a = fmaf(xA.z, w2, c0a); c0a = fmaf(xA.w, w3, c0a);
                c1a = fmaf(xB.x, w0, c1a); c1a = fmaf(xB.y, w1, c1a);
                c1a = fmaf(xB.z, w2, c1a); c1a = fmaf(xB.w, w3, c1a);
            }
            if (i < 15) {
                #pragma unroll
                for (int q = 0; q < 16; ++q) wv[q] = wn[q];
            }
        }
    }
    const float b3 = b_a3[col];
    out[(size_t)rA * 256 + col] = (c0a + b3) * mask[rA];
    out[(size_t)rB * 256 + col] = (c1a + b3) * mask[rB];
}

// ---------------------------------------------------------------------------
extern "C" void kernel_launch(void* const* d_in, const int* in_sizes, int n_in,
                              void* d_out, int out_size, void* d_ws, size_t ws_size,
                              hipStream_t stream) {
    const float* v    = (const float*)d_in[0];
    const float* dist = (const float*)d_in[1];
    const float* mask = (const float*)d_in[2];
    const float* W_s1 = (const float*)d_in[3];
    const float* b_s1 = (const float*)d_in[4];
    const float* W_s2 = (const float*)d_in[5];
    const float* b_s2 = (const float*)d_in[6];
    const float* W_a1 = (const float*)d_in[7];
    const float* b_a1 = (const float*)d_in[8];
    const float* W_a2 = (const float*)d_in[9];
    const float* b_a2 = (const float*)d_in[10];
    const float* W_a3 = (const float*)d_in[11];
    const float* b_a3 = (const float*)d_in[12];
    float* out = (float*)d_out;

    char* ws = (char*)d_ws;
    float*    v1 = (float*)(ws);                   // 2 MB
    uint16_t* T  = (uint16_t*)(ws + (2u << 20));   // 2 MB bf16 [4096][256]

    prep_kernel<<<768, 512, 0, stream>>>(v, mask, W_a1, b_a1, W_s1, b_s1, W_s2, b_s2, v1, T);
    main_kernel<<<512, 512, 0, stream>>>(dist, v1, T, mask, W_a2, b_a2, W_a3, b_a3, out);
}